// Round 1
// baseline (634.482 us; speedup 1.0000x reference)
//
#include <hip/hip_runtime.h>
#include <hip/hip_bf16.h>
#include <math.h>

// Problem constants (fixed by setup_inputs)
constexpr int B_ = 4, N_ = 4096, F_ = 256;
constexpr int DS = 80;

// ---------------------------------------------------------------------------
// init p/q max-index arrays to -1
__global__ void init_kernel(int* p, int* q) {
  int i = blockIdx.x * 256 + threadIdx.x;
  if (i < B_ * N_) { p[i] = -1; q[i] = -1; }
}

// ---------------------------------------------------------------------------
// sq[b][n] = sum_f x^2  (one wave per row)
__global__ __launch_bounds__(256) void sq_kernel(const float* __restrict__ x, float* __restrict__ sq) {
  int row = blockIdx.x * 4 + (threadIdx.x >> 6);
  int lane = threadIdx.x & 63;
  const float4 v = *(const float4*)&x[(size_t)row * F_ + lane * 4];
  float s = v.x * v.x + v.y * v.y + v.z * v.z + v.w * v.w;
  for (int off = 32; off > 0; off >>= 1) s += __shfl_down(s, off);
  if (lane == 0) sq[row] = s;
}

// ---------------------------------------------------------------------------
// Pairwise distances (lower triangle tiles, 64x64 per block), threshold, and
// max-index reductions:  p[i] = max{j<i adj}, q[i] = max{j adj} (symmetric).
__global__ __launch_bounds__(256) void dist_kernel(const float* __restrict__ x,
                                                   const float* __restrict__ sq,
                                                   int* __restrict__ p, int* __restrict__ q) {
  int tj = blockIdx.x, ti = blockIdx.y, b = blockIdx.z;
  if (tj > ti) return;  // lower triangle only
  const int i0 = ti * 64, j0 = tj * 64;
  __shared__ __align__(16) float Xi[32][68];
  __shared__ __align__(16) float Xj[32][68];
  __shared__ int smq[64], smp[64], scq[64];
  const int tid = threadIdx.x;
  const int tx = tid & 15, ty = tid >> 4;
  float acc[4][4] = {};
  const float* xb = x + (size_t)b * N_ * F_;

  for (int f0 = 0; f0 < F_; f0 += 32) {
    const int fc = tid & 31, r0 = tid >> 5;  // 8 rows per pass
#pragma unroll
    for (int rr = 0; rr < 64; rr += 8) {
      Xi[fc][r0 + rr] = xb[(size_t)(i0 + r0 + rr) * F_ + f0 + fc];
      Xj[fc][r0 + rr] = xb[(size_t)(j0 + r0 + rr) * F_ + f0 + fc];
    }
    __syncthreads();
#pragma unroll
    for (int f = 0; f < 32; ++f) {
      float4 av = *(const float4*)&Xi[f][ty * 4];
      float4 bv = *(const float4*)&Xj[f][tx * 4];
      acc[0][0] += av.x * bv.x; acc[0][1] += av.x * bv.y; acc[0][2] += av.x * bv.z; acc[0][3] += av.x * bv.w;
      acc[1][0] += av.y * bv.x; acc[1][1] += av.y * bv.y; acc[1][2] += av.y * bv.z; acc[1][3] += av.y * bv.w;
      acc[2][0] += av.z * bv.x; acc[2][1] += av.z * bv.y; acc[2][2] += av.z * bv.z; acc[2][3] += av.z * bv.w;
      acc[3][0] += av.w * bv.x; acc[3][1] += av.w * bv.y; acc[3][2] += av.w * bv.z; acc[3][3] += av.w * bv.w;
    }
    __syncthreads();
  }

  // threshold: sqrt(max(d2,0)) < 22.63f  <=>  d2 < (22.63f)^2 (nonneg)
  const double THR = (double)22.63f;
  const double THR2 = THR * THR;
  float sqi[4], sqj[4];
#pragma unroll
  for (int ii = 0; ii < 4; ++ii) sqi[ii] = sq[(size_t)b * N_ + i0 + ty * 4 + ii];
#pragma unroll
  for (int jj = 0; jj < 4; ++jj) sqj[jj] = sq[(size_t)b * N_ + j0 + tx * 4 + jj];

  int rq[4] = {-1, -1, -1, -1}, rp[4] = {-1, -1, -1, -1}, cq[4] = {-1, -1, -1, -1};
#pragma unroll
  for (int ii = 0; ii < 4; ++ii) {
    int gi = i0 + ty * 4 + ii;
#pragma unroll
    for (int jj = 0; jj < 4; ++jj) {
      int gj = j0 + tx * 4 + jj;
      double d2 = (double)sqi[ii] + (double)sqj[jj] - 2.0 * (double)acc[ii][jj];
      bool adj = d2 < THR2;
      if (adj) {
        rq[ii] = max(rq[ii], gj);
        if (gj < gi) rp[ii] = max(rp[ii], gj);
        cq[jj] = max(cq[jj], gi);
      }
    }
  }
  if (tid < 64) { smq[tid] = -1; smp[tid] = -1; scq[tid] = -1; }
  __syncthreads();
#pragma unroll
  for (int ii = 0; ii < 4; ++ii) {
    if (rq[ii] >= 0) atomicMax(&smq[ty * 4 + ii], rq[ii]);
    if (rp[ii] >= 0) atomicMax(&smp[ty * 4 + ii], rp[ii]);
  }
#pragma unroll
  for (int jj = 0; jj < 4; ++jj)
    if (cq[jj] >= 0) atomicMax(&scq[tx * 4 + jj], cq[jj]);
  __syncthreads();
  if (tid < 64) {
    if (smq[tid] >= 0) atomicMax(&q[(size_t)b * N_ + i0 + tid], smq[tid]);
    if (smp[tid] >= 0) atomicMax(&p[(size_t)b * N_ + i0 + tid], smp[tid]);
    if (scq[tid] >= 0) atomicMax(&q[(size_t)b * N_ + j0 + tid], scq[tid]);
  }
}

// ---------------------------------------------------------------------------
// Per batch: root-chase p via pointer doubling, rank roots (1-based, row
// order == fresh-label order), then labels[j] = rank[root(q(j))].
__global__ __launch_bounds__(1024) void label_kernel(const int* __restrict__ p,
                                                     const int* __restrict__ q,
                                                     int* __restrict__ lab) {
  const int b = blockIdx.x, tid = threadIdx.x;
  __shared__ int A[N_], Bb[N_];
  __shared__ int waveOff[17];
  __shared__ int runBase;
  for (int k = tid; k < N_; k += 1024) {
    int pi = p[(size_t)b * N_ + k];
    A[k] = (pi < 0) ? k : pi;  // roots are fixed points (p[i] < i when >=0)
  }
  __syncthreads();
  int* src = A; int* dst = Bb;
  for (int it = 0; it < 12; ++it) {  // 2^12 >= max chain length
    for (int k = tid; k < N_; k += 1024) dst[k] = src[src[k]];
    __syncthreads();
    int* t = src; src = dst; dst = t;
  }
  // src[i] = root(i); dst free -> inclusive rank of isRoot
  if (tid == 0) runBase = 0;
  __syncthreads();
  for (int base = 0; base < N_; base += 1024) {
    int i = base + tid;
    bool isR = (src[i] == i);
    unsigned long long bal = __ballot(isR);
    int lane = tid & 63, wid = tid >> 6;
    if (lane == 0) waveOff[wid] = __popcll(bal);
    __syncthreads();
    if (tid == 0) {
      int s = runBase;
      for (int w = 0; w < 16; ++w) { int t = waveOff[w]; waveOff[w] = s; s += t; }
      waveOff[16] = s;
    }
    __syncthreads();
    int incl = __popcll(bal & (~0ull >> (63 - lane)));
    dst[i] = waveOff[wid] + incl;
    __syncthreads();
    if (tid == 0) runBase = waveOff[16];
    __syncthreads();
  }
  for (int j = tid; j < N_; j += 1024) {
    int qq = q[(size_t)b * N_ + j];
    lab[(size_t)b * N_ + j] = dst[src[qq]];  // local (per-batch) label, 1-based
  }
}

// ---------------------------------------------------------------------------
// Per batch: histogram labels, compact present labels ascending (np.unique
// order), sizes, offsets, and stable (ascending-j) member lists.
__global__ __launch_bounds__(1024) void build_kernel(const int* __restrict__ lab,
                                                     int* __restrict__ Karr, int* __restrict__ labs,
                                                     int* __restrict__ Msz, int* __restrict__ offs,
                                                     int* __restrict__ members) {
  const int b = blockIdx.x, tid = threadIdx.x;
  __shared__ int cnt[N_ + 1];
  __shared__ int waveOff[17];
  __shared__ int runBase, sK;
  for (int k = tid; k <= N_; k += 1024) cnt[k] = 0;
  __syncthreads();
  for (int j = tid; j < N_; j += 1024) atomicAdd(&cnt[lab[(size_t)b * N_ + j]], 1);
  __syncthreads();
  // compact present labels (1..N) ascending
  if (tid == 0) runBase = 0;
  __syncthreads();
  for (int base = 1; base <= N_; base += 1024) {
    int c = base + tid;
    bool m = (cnt[c] > 0);
    unsigned long long bal = __ballot(m);
    int lane = tid & 63, wid = tid >> 6;
    if (lane == 0) waveOff[wid] = __popcll(bal);
    __syncthreads();
    if (tid == 0) {
      int s = runBase;
      for (int w = 0; w < 16; ++w) { int t = waveOff[w]; waveOff[w] = s; s += t; }
      waveOff[16] = s;
    }
    __syncthreads();
    if (m) {
      int pos = waveOff[wid] + __popcll(bal & ((1ull << lane) - 1));
      labs[(size_t)b * N_ + pos] = c;
      Msz[(size_t)b * N_ + pos] = cnt[c];
    }
    __syncthreads();
    if (tid == 0) runBase = waveOff[16];
    __syncthreads();
  }
  if (tid == 0) {
    sK = runBase;
    Karr[b] = sK;
    int s = 0;
    for (int k = 0; k < sK; ++k) { offs[(size_t)b * N_ + k] = s; s += Msz[(size_t)b * N_ + k]; }
  }
  __syncthreads();
  int K = sK;
  for (int k = 0; k < K; ++k) {
    int c = labs[(size_t)b * N_ + k];
    int baseOff = offs[(size_t)b * N_ + k];
    if (tid == 0) runBase = 0;
    __syncthreads();
    for (int base = 0; base < N_; base += 1024) {
      int j = base + tid;
      bool m = (lab[(size_t)b * N_ + j] == c);
      unsigned long long bal = __ballot(m);
      int lane = tid & 63, wid = tid >> 6;
      if (lane == 0) waveOff[wid] = __popcll(bal);
      __syncthreads();
      if (tid == 0) {
        int s = runBase;
        for (int w = 0; w < 16; ++w) { int t = waveOff[w]; waveOff[w] = s; s += t; }
        waveOff[16] = s;
      }
      __syncthreads();
      if (m) members[(size_t)b * N_ + baseOff + waveOff[wid] + __popcll(bal & ((1ull << lane) - 1))] = j;
      __syncthreads();
      if (tid == 0) runBase = waveOff[16];
      __syncthreads();
    }
  }
}

// ---------------------------------------------------------------------------
// Single block: MT19937 (numpy RandomState(0)) masked-rejection choice, gather,
// PointNet-lite classify, BCE accumulate. Strictly sequential over (b, k).
__global__ __launch_bounds__(256) void classify_kernel(
    const float* __restrict__ points, const float* __restrict__ W1, const float* __restrict__ b1,
    const float* __restrict__ W2, const float* __restrict__ b2,
    const float* __restrict__ W3, const float* __restrict__ b3,
    const int* __restrict__ Karr, const int* __restrict__ Msz, const int* __restrict__ offs,
    const int* __restrict__ members, float* __restrict__ out) {
  const int tid = threadIdx.x;
  __shared__ unsigned int mt[624];
  __shared__ int mtIdx;
  __shared__ int sel[DS];
  __shared__ float pts[DS][3];
  __shared__ float h1[DS][64];
  __shared__ float W2s[64][128];
  __shared__ float gmax[128];

  for (int k = tid; k < 64 * 128; k += 256) W2s[k >> 7][k & 127] = W2[k];
  if (tid == 0) {  // numpy init_genrand(0)
    mt[0] = 0u;
    for (int i = 1; i < 624; ++i) mt[i] = 1812433253u * (mt[i - 1] ^ (mt[i - 1] >> 30)) + (unsigned)i;
    mtIdx = 624;
  }
  __syncthreads();

  float total = 0.f;
  for (int b = 0; b < B_; ++b) {
    int K = Karr[b];
    float lsum = 0.f;
    for (int k = 0; k < K; ++k) {
      int M = Msz[(size_t)b * N_ + k];
      int base = offs[(size_t)b * N_ + k];
      if (tid == 0) {
        if (M <= 1) {
          for (int t = 0; t < DS; ++t) sel[t] = 0;  // rng==0: no draws consumed
        } else {
          unsigned rng = (unsigned)(M - 1);
          unsigned mask = rng;
          mask |= mask >> 1; mask |= mask >> 2; mask |= mask >> 4; mask |= mask >> 8; mask |= mask >> 16;
          for (int t = 0; t < DS; ++t) {
            unsigned v;
            do {
              if (mtIdx >= 624) {
                for (int i = 0; i < 624; ++i) {
                  unsigned y = (mt[i] & 0x80000000u) | (mt[(i + 1) % 624] & 0x7fffffffu);
                  mt[i] = mt[(i + 397) % 624] ^ (y >> 1) ^ ((y & 1u) ? 0x9908b0dfu : 0u);
                }
                mtIdx = 0;
              }
              unsigned y = mt[mtIdx++];
              y ^= y >> 11; y ^= (y << 7) & 0x9d2c5680u; y ^= (y << 15) & 0xefc60000u; y ^= y >> 18;
              v = y & mask;
            } while (v > rng);
            sel[t] = (int)v;
          }
        }
      }
      __syncthreads();
      if (tid < DS) {
        int mi = members[(size_t)b * N_ + base + sel[tid]];
        pts[tid][0] = points[((size_t)b * N_ + mi) * 3 + 0];
        pts[tid][1] = points[((size_t)b * N_ + mi) * 3 + 1];
        pts[tid][2] = points[((size_t)b * N_ + mi) * 3 + 2];
      }
      __syncthreads();
      for (int o = tid; o < DS * 64; o += 256) {
        int r = o >> 6, c = o & 63;
        float v = pts[r][0] * W1[c] + pts[r][1] * W1[64 + c] + pts[r][2] * W1[128 + c] + b1[c];
        h1[r][c] = fmaxf(v, 0.f);
      }
      __syncthreads();
      if (tid < 128) {
        int c = tid;
        float b2c = b2[c];
        float m = -1e30f;
        for (int r = 0; r < DS; ++r) {
          float a0 = 0.f, a1 = 0.f, a2 = 0.f, a3 = 0.f;
#pragma unroll
          for (int kk = 0; kk < 64; kk += 4) {
            a0 += h1[r][kk + 0] * W2s[kk + 0][c];
            a1 += h1[r][kk + 1] * W2s[kk + 1][c];
            a2 += h1[r][kk + 2] * W2s[kk + 2][c];
            a3 += h1[r][kk + 3] * W2s[kk + 3][c];
          }
          float acc = ((a0 + a1) + (a2 + a3)) + b2c;
          m = fmaxf(m, fmaxf(acc, 0.f));
        }
        gmax[c] = m;
      }
      __syncthreads();
      if (tid == 0) {
        float l0 = b3[0], l1 = b3[1];
        for (int c = 0; c < 128; ++c) { l0 += gmax[c] * W3[c * 2 + 0]; l1 += gmax[c] * W3[c * 2 + 1]; }
        float mx = fmaxf(l0, l1);
        float e0 = expf(l0 - mx), e1 = expf(l1 - mx);
        float p1 = e1 / (e0 + e1);
        if (isnan(p1)) p1 = 0.f;  // jnp.nan_to_num
        lsum += fminf(-logf(p1), 100.f);
      }
      __syncthreads();
    }
    if (tid == 0) total += lsum / (float)K;
  }
  if (tid == 0) out[0] = total;
}

// ---------------------------------------------------------------------------
extern "C" void kernel_launch(void* const* d_in, const int* in_sizes, int n_in,
                              void* d_out, int out_size, void* d_ws, size_t ws_size,
                              hipStream_t stream) {
  const float* x      = (const float*)d_in[0];  // point_features [4,4096,256]
  const float* points = (const float*)d_in[1];  // [4,4096,3]
  const float* W1 = (const float*)d_in[2];
  const float* b1 = (const float*)d_in[3];
  const float* W2 = (const float*)d_in[4];
  const float* b2 = (const float*)d_in[5];
  const float* W3 = (const float*)d_in[6];
  const float* b3 = (const float*)d_in[7];
  float* out = (float*)d_out;

  char* ws = (char*)d_ws;
  float* sq    = (float*)ws; ws += (size_t)B_ * N_ * 4;
  int* p       = (int*)ws;   ws += (size_t)B_ * N_ * 4;
  int* q       = (int*)ws;   ws += (size_t)B_ * N_ * 4;
  int* lab     = (int*)ws;   ws += (size_t)B_ * N_ * 4;
  int* members = (int*)ws;   ws += (size_t)B_ * N_ * 4;
  int* labs    = (int*)ws;   ws += (size_t)B_ * N_ * 4;
  int* Msz     = (int*)ws;   ws += (size_t)B_ * N_ * 4;
  int* offs    = (int*)ws;   ws += (size_t)B_ * N_ * 4;
  int* Karr    = (int*)ws;   ws += 64 * 4;

  hipLaunchKernelGGL(init_kernel, dim3((B_ * N_ + 255) / 256), dim3(256), 0, stream, p, q);
  hipLaunchKernelGGL(sq_kernel, dim3(B_ * N_ / 4), dim3(256), 0, stream, x, sq);
  hipLaunchKernelGGL(dist_kernel, dim3(64, 64, B_), dim3(256), 0, stream, x, sq, p, q);
  hipLaunchKernelGGL(label_kernel, dim3(B_), dim3(1024), 0, stream, p, q, lab);
  hipLaunchKernelGGL(build_kernel, dim3(B_), dim3(1024), 0, stream, lab, Karr, labs, Msz, offs, members);
  hipLaunchKernelGGL(classify_kernel, dim3(1), dim3(256), 0, stream,
                     points, W1, b1, W2, b2, W3, b3, Karr, Msz, offs, members, out);
}